// Round 12
// baseline (250.522 us; speedup 1.0000x reference)
//
#include <hip/hip_runtime.h>
#include <hip/hip_bf16.h>
#include <hip/hip_fp16.h>

// Problem constants: N=12288, E=393216, D=256, K=16
#define D 256
#define KCL 16
#define EPS 1e-15f
#define PAD 128            // ELL capacity; max degree (Poisson lambda=32) << 128

typedef __attribute__((ext_vector_type(8))) short short8;
typedef __attribute__((ext_vector_type(8))) _Float16 half8;
typedef __attribute__((ext_vector_type(4))) float f32x4;

// ---------------- setup: weight prep fp16 [c][k] (blocks 0..511) + ELL scatter --
__global__ __launch_bounds__(256) void setup_k(const float* __restrict__ W1,
                                               const float* __restrict__ W2,
                                               __half* __restrict__ Wt1,
                                               __half* __restrict__ Wt2,
                                               const int* __restrict__ src,
                                               const int* __restrict__ dst,
                                               const float* __restrict__ ew,
                                               int* __restrict__ deg,
                                               int2* __restrict__ edges, int E) {
    int b = blockIdx.x;
    if (b < 512) {
        const float* W = (b < 256) ? W1 : W2;
        __half* T = (b < 256) ? Wt1 : Wt2;
        int c = b & 255;
        int k = threadIdx.x;
        T[(size_t)c * D + k] = __float2half(W[(size_t)k * D + c]);
    } else {
        int e = (b - 512) * 256 + threadIdx.x;
        if (e < E) {
            int d = dst[e];
            int slot = atomicAdd(&deg[d], 1);
            if (slot < PAD)
                edges[(size_t)d * PAD + slot] = make_int2(src[e], __float_as_int(ew[e]));
        }
    }
}

// ---------------- fp16 MFMA GEMM: C[M,256] = fp16(A) @ fp16(B), fp16 out --------
// B pre-transposed fp16 [col][k]; B fragments read straight from global (L2-hot).
__device__ __forceinline__ short8 ld8h(const float* p) {
    float4 v0 = *(const float4*)p;
    float4 v1 = *(const float4*)(p + 4);
    float vv[8] = {v0.x, v0.y, v0.z, v0.w, v1.x, v1.y, v1.z, v1.w};
    short8 o;
#pragma unroll
    for (int j = 0; j < 8; ++j) {
        _Float16 h = (_Float16)vv[j];
        o[j] = __builtin_bit_cast(short, h);
    }
    return o;
}
__device__ __forceinline__ short8 ld8h(const __half* p) {
    return *(const short8*)p;
}

template<typename T>
__global__ __launch_bounds__(256) void gemm_k(const T* __restrict__ A,
                                              const __half* __restrict__ Bt,
                                              __half* __restrict__ C) {
    __shared__ short Ah[64][40];          // fp16 bits, 80B row stride
    int tid = threadIdx.x;
    int lane = tid & 63, w = tid >> 6;
    int bm = blockIdx.x * 64, bn = blockIdx.y * 64;
    f32x4 acc[4];
#pragma unroll
    for (int i = 0; i < 4; ++i) acc[i] = (f32x4){0.f, 0.f, 0.f, 0.f};

    int r  = tid >> 2;             // A-stage row 0..63
    int cc = (tid & 3) * 8;        // A-stage k-chunk
    int ar = w * 16 + (lane & 15); // A-frag row
    int kq = (lane >> 4) * 8;      // frag k-chunk

    for (int kk = 0; kk < D; kk += 32) {
        short8 a8 = ld8h(&A[(size_t)(bm + r) * D + kk + cc]);
        __syncthreads();                       // WAR: prev-iter reads done
        *(short8*)&Ah[r][cc] = a8;
        __syncthreads();

        half8 av = __builtin_bit_cast(half8, *(const short8*)&Ah[ar][kq]);
#pragma unroll
        for (int nf = 0; nf < 4; ++nf) {
            int col = bn + nf * 16 + (lane & 15);
            half8 bv = __builtin_bit_cast(half8,
                        *(const short8*)&Bt[(size_t)col * D + kk + kq]);
            acc[nf] = __builtin_amdgcn_mfma_f32_16x16x32_f16(av, bv, acc[nf], 0, 0, 0);
        }
    }
    // epilogue: C/D layout col=lane&15, row=(lane>>4)*4+rr  [m89-verified]
    int rbase = bm + w * 16 + (lane >> 4) * 4;
    int cb = bn + (lane & 15);
#pragma unroll
    for (int nf = 0; nf < 4; ++nf)
#pragma unroll
        for (int rr = 0; rr < 4; ++rr)
            C[(size_t)(rbase + rr) * D + cb + nf * 16] = __float2half(acc[nf][rr]);
}

// ---------------- SpMM (ELL by dst), half2 gather + bias + ReLU, fp16 out -------
__global__ __launch_bounds__(128) void spmm_k(const __half* __restrict__ h,
                                              const int2* __restrict__ edges,
                                              const int* __restrict__ deg,
                                              const float* __restrict__ bias,
                                              __half* __restrict__ out) {
    int node = blockIdx.x;
    int t = threadIdx.x;                 // 0..127; features 2t, 2t+1
    int n = min(deg[node], PAD);
    __shared__ int2 se[PAD];
    if (t < n) se[t] = edges[(size_t)node * PAD + t];
    __syncthreads();
    const __half2* h2 = (const __half2*)h;   // row stride D/2
    float acc0 = 0.f, acc1 = 0.f;
    int i = 0;
    for (; i + 4 <= n; i += 4) {
        int2 e0 = se[i], e1 = se[i + 1], e2 = se[i + 2], e3 = se[i + 3];
        float2 a0 = __half22float2(h2[(size_t)e0.x * (D / 2) + t]);
        float2 a1 = __half22float2(h2[(size_t)e1.x * (D / 2) + t]);
        float2 a2 = __half22float2(h2[(size_t)e2.x * (D / 2) + t]);
        float2 a3 = __half22float2(h2[(size_t)e3.x * (D / 2) + t]);
        float w0 = __int_as_float(e0.y), w1 = __int_as_float(e1.y);
        float w2 = __int_as_float(e2.y), w3 = __int_as_float(e3.y);
        acc0 = fmaf(w0, a0.x, acc0); acc1 = fmaf(w0, a0.y, acc1);
        acc0 = fmaf(w1, a1.x, acc0); acc1 = fmaf(w1, a1.y, acc1);
        acc0 = fmaf(w2, a2.x, acc0); acc1 = fmaf(w2, a2.y, acc1);
        acc0 = fmaf(w3, a3.x, acc0); acc1 = fmaf(w3, a3.y, acc1);
    }
    for (; i < n; ++i) {
        int2 e = se[i];
        float2 a = __half22float2(h2[(size_t)e.x * (D / 2) + t]);
        float wv = __int_as_float(e.y);
        acc0 = fmaf(wv, a.x, acc0); acc1 = fmaf(wv, a.y, acc1);
    }
    float2 bv = *(const float2*)&bias[2 * t];
    float f0 = fmaxf(acc0 + bv.x, 0.f), f1 = fmaxf(acc1 + bv.y, 0.f);
    ((__half2*)out)[(size_t)node * (D / 2) + t] = __float22half2_rn(make_float2(f0, f1));
}

// ------ SpMM conv2 + fused cluster MLP + softmax (H2 never materialized) --------
__global__ __launch_bounds__(128) void spmm_cluster_k(const __half* __restrict__ h,
                                                      const int2* __restrict__ edges,
                                                      const int* __restrict__ deg,
                                                      const float* __restrict__ bias,
                                                      const float* __restrict__ Wm,
                                                      const float* __restrict__ bmv,
                                                      float* __restrict__ s_out) {
    int node = blockIdx.x;
    int t = threadIdx.x;                 // 0..127; features 2t, 2t+1
    int n = min(deg[node], PAD);
    __shared__ int2 se[PAD];
    if (t < n) se[t] = edges[(size_t)node * PAD + t];
    __syncthreads();
    const __half2* h2 = (const __half2*)h;
    float acc0 = 0.f, acc1 = 0.f;
    int i = 0;
    for (; i + 4 <= n; i += 4) {
        int2 e0 = se[i], e1 = se[i + 1], e2 = se[i + 2], e3 = se[i + 3];
        float2 a0 = __half22float2(h2[(size_t)e0.x * (D / 2) + t]);
        float2 a1 = __half22float2(h2[(size_t)e1.x * (D / 2) + t]);
        float2 a2 = __half22float2(h2[(size_t)e2.x * (D / 2) + t]);
        float2 a3 = __half22float2(h2[(size_t)e3.x * (D / 2) + t]);
        float w0 = __int_as_float(e0.y), w1 = __int_as_float(e1.y);
        float w2 = __int_as_float(e2.y), w3 = __int_as_float(e3.y);
        acc0 = fmaf(w0, a0.x, acc0); acc1 = fmaf(w0, a0.y, acc1);
        acc0 = fmaf(w1, a1.x, acc0); acc1 = fmaf(w1, a1.y, acc1);
        acc0 = fmaf(w2, a2.x, acc0); acc1 = fmaf(w2, a2.y, acc1);
        acc0 = fmaf(w3, a3.x, acc0); acc1 = fmaf(w3, a3.y, acc1);
    }
    for (; i < n; ++i) {
        int2 e = se[i];
        float2 a = __half22float2(h2[(size_t)e.x * (D / 2) + t]);
        float wv = __int_as_float(e.y);
        acc0 = fmaf(wv, a.x, acc0); acc1 = fmaf(wv, a.y, acc1);
    }
    float2 bv = *(const float2*)&bias[2 * t];
    float f0 = fmaxf(acc0 + bv.x, 0.f), f1 = fmaxf(acc1 + bv.y, 0.f);

    // partial logits: this thread's two features x Wm rows 2t, 2t+1
    float pl[KCL];
    const float4* w0 = (const float4*)&Wm[(size_t)(2 * t) * KCL];
    const float4* w1 = (const float4*)&Wm[(size_t)(2 * t + 1) * KCL];
#pragma unroll
    for (int q = 0; q < 4; ++q) {
        float4 a = w0[q], b = w1[q];
        pl[q * 4 + 0] = f0 * a.x + f1 * b.x;
        pl[q * 4 + 1] = f0 * a.y + f1 * b.y;
        pl[q * 4 + 2] = f0 * a.z + f1 * b.z;
        pl[q * 4 + 3] = f0 * a.w + f1 * b.w;
    }
    // wave butterfly reduce (64 lanes)
#pragma unroll
    for (int off = 32; off; off >>= 1)
#pragma unroll
        for (int j = 0; j < KCL; ++j) pl[j] += __shfl_xor(pl[j], off, 64);
    // cross-wave combine (2 waves)
    __shared__ float xw[2][KCL];
    int wv = t >> 6, ln = t & 63;
    if (ln == 0) {
#pragma unroll
        for (int j = 0; j < KCL; ++j) xw[wv][j] = pl[j];
    }
    __syncthreads();
    if (t == 0) {
        float p[KCL];
        float mx = -1e30f;
#pragma unroll
        for (int j = 0; j < KCL; ++j) {
            p[j] = xw[0][j] + xw[1][j] + bmv[j];
            mx = fmaxf(mx, p[j]);
        }
        float sum = 0.f;
#pragma unroll
        for (int j = 0; j < KCL; ++j) { p[j] = __expf(p[j] - mx); sum += p[j]; }
        float inv = 1.f / sum;
        float* so = &s_out[(size_t)node * KCL];
#pragma unroll
        for (int q = 0; q < 4; ++q)
            *(float4*)&so[q * 4] = make_float4(p[q*4+0] * inv, p[q*4+1] * inv,
                                               p[q*4+2] * inv, p[q*4+3] * inv);
    }
}

// ------- final: loss from s directly (coalesced read of N*16 floats) ------------
__global__ __launch_bounds__(1024) void final_k(const float* __restrict__ s,
                                                float* __restrict__ loss_out, int N) {
    int tid = threadIdx.x;                   // 0..1023
    int total = N * KCL;
    float acc = 0.f;
    for (int idx = tid; idx < total; idx += 1024) {  // idx&15 fixed per thread
        float v = s[idx];
        acc = fmaf(v, v, acc);
    }
    int j = tid & 15, g = tid >> 4;          // 64 groups
    __shared__ float red[64][KCL + 1];
    red[g][j] = acc;
    __syncthreads();
    if (tid < KCL) {
        float v = 0.f;
#pragma unroll
        for (int gg = 0; gg < 64; ++gg) v += red[gg][tid];
        red[0][tid] = sqrtf(v + EPS);
    }
    __syncthreads();
    if (tid == 0) {
        float sum = 0.f;
#pragma unroll
        for (int jj = 0; jj < KCL; ++jj) sum += red[0][jj];
        loss_out[0] = -sum / sqrtf((float)N * (float)KCL);
    }
}

extern "C" void kernel_launch(void* const* d_in, const int* in_sizes, int n_in,
                              void* d_out, int out_size, void* d_ws, size_t ws_size,
                              hipStream_t stream) {
    const float* x  = (const float*)d_in[0];
    const float* ew = (const float*)d_in[1];
    const float* W1 = (const float*)d_in[2];
    const float* b1 = (const float*)d_in[3];
    const float* W2 = (const float*)d_in[4];
    const float* b2 = (const float*)d_in[5];
    const float* Wm = (const float*)d_in[6];
    const float* bm = (const float*)d_in[7];
    const int*   ei = (const int*)d_in[8];

    const int N = in_sizes[0] / D;       // 12288
    const int E = in_sizes[1];           // 393216
    const int* src = ei;
    const int* dst = ei + E;

    float* out = (float*)d_out;

    // ws layout
    char* ws = (char*)d_ws;
    __half* G    = (__half*)ws;       ws += (size_t)N * D * 2;      // gemm out (fp16)
    __half* H1   = (__half*)ws;       ws += (size_t)N * D * 2;      // conv1 out (fp16)
    int*   deg   = (int*)ws;          ws += (size_t)N * 4;
    int2*  edges = (int2*)ws;         ws += (size_t)N * PAD * 8;
    __half* Wt1  = (__half*)ws;       ws += (size_t)D * D * 2;
    __half* Wt2  = (__half*)ws;       ws += (size_t)D * D * 2;

    // zero deg
    hipMemsetAsync(deg, 0, (size_t)N * 4, stream);
    // fused weight prep + ELL scatter
    int gE = (E + 255) / 256;
    setup_k<<<512 + gE, 256, 0, stream>>>(W1, W2, Wt1, Wt2,
                                          src, dst, ew, deg, edges, E);

    dim3 ggrid(N / 64, 4);
    // conv1: G = fp16(x @ W1) ; H1 = fp16(relu(scatter(G) + b1))
    gemm_k<float><<<ggrid, 256, 0, stream>>>(x, Wt1, G);
    spmm_k<<<N, 128, 0, stream>>>(G, edges, deg, b1, H1);
    // conv2 gemm: G = fp16(H1 @ W2)
    gemm_k<__half><<<ggrid, 256, 0, stream>>>(H1, Wt2, G);
    // conv2 scatter + cluster MLP + softmax -> s (d_out); H2 never stored
    spmm_cluster_k<<<N, 128, 0, stream>>>(G, edges, deg, b2, Wm, bm, out);
    // loss from s
    final_k<<<1, 1024, 0, stream>>>(out, out + (size_t)N * KCL, N);
}

// Round 13
// 214.387 us; speedup vs baseline: 1.1686x; 1.1686x over previous
//
#include <hip/hip_runtime.h>
#include <hip/hip_bf16.h>
#include <hip/hip_fp16.h>

// Problem constants: N=12288, E=393216, D=256, K=16
#define D 256
#define KCL 16
#define EPS 1e-15f
#define PAD 128            // ELL capacity; max degree (Poisson lambda=32) << 128

typedef __attribute__((ext_vector_type(8))) short short8;
typedef __attribute__((ext_vector_type(8))) _Float16 half8;
typedef __attribute__((ext_vector_type(4))) float f32x4;

// ---------------- setup: weight prep fp16 [c][k] (blocks 0..511) + ELL scatter --
__global__ __launch_bounds__(256) void setup_k(const float* __restrict__ W1,
                                               const float* __restrict__ W2,
                                               __half* __restrict__ Wt1,
                                               __half* __restrict__ Wt2,
                                               const int* __restrict__ src,
                                               const int* __restrict__ dst,
                                               const float* __restrict__ ew,
                                               int* __restrict__ deg,
                                               int2* __restrict__ edges, int E) {
    int b = blockIdx.x;
    if (b < 512) {
        const float* W = (b < 256) ? W1 : W2;
        __half* T = (b < 256) ? Wt1 : Wt2;
        int c = b & 255;
        int k = threadIdx.x;
        T[(size_t)c * D + k] = __float2half(W[(size_t)k * D + c]);
    } else {
        int e = (b - 512) * 256 + threadIdx.x;
        if (e < E) {
            int d = dst[e];
            int slot = atomicAdd(&deg[d], 1);
            if (slot < PAD)
                edges[(size_t)d * PAD + slot] = make_int2(src[e], __float_as_int(ew[e]));
        }
    }
}

// ---------------- fp16 MFMA GEMM: C[M,256] = fp16(A) @ fp16(B), fp16 out --------
// B pre-transposed fp16 [col][k]; B fragments read straight from global (L2-hot).
__device__ __forceinline__ short8 ld8h(const float* p) {
    float4 v0 = *(const float4*)p;
    float4 v1 = *(const float4*)(p + 4);
    float vv[8] = {v0.x, v0.y, v0.z, v0.w, v1.x, v1.y, v1.z, v1.w};
    short8 o;
#pragma unroll
    for (int j = 0; j < 8; ++j) {
        _Float16 h = (_Float16)vv[j];
        o[j] = __builtin_bit_cast(short, h);
    }
    return o;
}
__device__ __forceinline__ short8 ld8h(const __half* p) {
    return *(const short8*)p;
}

template<typename T>
__global__ __launch_bounds__(256) void gemm_k(const T* __restrict__ A,
                                              const __half* __restrict__ Bt,
                                              __half* __restrict__ C) {
    __shared__ short Ah[64][40];          // fp16 bits, 80B row stride
    int tid = threadIdx.x;
    int lane = tid & 63, w = tid >> 6;
    int bm = blockIdx.x * 64, bn = blockIdx.y * 64;
    f32x4 acc[4];
#pragma unroll
    for (int i = 0; i < 4; ++i) acc[i] = (f32x4){0.f, 0.f, 0.f, 0.f};

    int r  = tid >> 2;             // A-stage row 0..63
    int cc = (tid & 3) * 8;        // A-stage k-chunk
    int ar = w * 16 + (lane & 15); // A-frag row
    int kq = (lane >> 4) * 8;      // frag k-chunk

    for (int kk = 0; kk < D; kk += 32) {
        short8 a8 = ld8h(&A[(size_t)(bm + r) * D + kk + cc]);
        __syncthreads();                       // WAR: prev-iter reads done
        *(short8*)&Ah[r][cc] = a8;
        __syncthreads();

        half8 av = __builtin_bit_cast(half8, *(const short8*)&Ah[ar][kq]);
#pragma unroll
        for (int nf = 0; nf < 4; ++nf) {
            int col = bn + nf * 16 + (lane & 15);
            half8 bv = __builtin_bit_cast(half8,
                        *(const short8*)&Bt[(size_t)col * D + kk + kq]);
            acc[nf] = __builtin_amdgcn_mfma_f32_16x16x32_f16(av, bv, acc[nf], 0, 0, 0);
        }
    }
    // epilogue: C/D layout col=lane&15, row=(lane>>4)*4+rr  [m89-verified]
    int rbase = bm + w * 16 + (lane >> 4) * 4;
    int cb = bn + (lane & 15);
#pragma unroll
    for (int nf = 0; nf < 4; ++nf)
#pragma unroll
        for (int rr = 0; rr < 4; ++rr)
            C[(size_t)(rbase + rr) * D + cb + nf * 16] = __float2half(acc[nf][rr]);
}

// ---------------- SpMM (ELL by dst), half2 gather + bias + ReLU, fp16 out -------
__global__ __launch_bounds__(128) void spmm_k(const __half* __restrict__ h,
                                              const int2* __restrict__ edges,
                                              const int* __restrict__ deg,
                                              const float* __restrict__ bias,
                                              __half* __restrict__ out) {
    int node = blockIdx.x;
    int t = threadIdx.x;                 // 0..127; features 2t, 2t+1
    int n = min(deg[node], PAD);
    __shared__ int2 se[PAD];
    if (t < n) se[t] = edges[(size_t)node * PAD + t];
    __syncthreads();
    const __half2* h2 = (const __half2*)h;   // row stride D/2
    float acc0 = 0.f, acc1 = 0.f;
    int i = 0;
    for (; i + 4 <= n; i += 4) {
        int2 e0 = se[i], e1 = se[i + 1], e2 = se[i + 2], e3 = se[i + 3];
        float2 a0 = __half22float2(h2[(size_t)e0.x * (D / 2) + t]);
        float2 a1 = __half22float2(h2[(size_t)e1.x * (D / 2) + t]);
        float2 a2 = __half22float2(h2[(size_t)e2.x * (D / 2) + t]);
        float2 a3 = __half22float2(h2[(size_t)e3.x * (D / 2) + t]);
        float w0 = __int_as_float(e0.y), w1 = __int_as_float(e1.y);
        float w2 = __int_as_float(e2.y), w3 = __int_as_float(e3.y);
        acc0 = fmaf(w0, a0.x, acc0); acc1 = fmaf(w0, a0.y, acc1);
        acc0 = fmaf(w1, a1.x, acc0); acc1 = fmaf(w1, a1.y, acc1);
        acc0 = fmaf(w2, a2.x, acc0); acc1 = fmaf(w2, a2.y, acc1);
        acc0 = fmaf(w3, a3.x, acc0); acc1 = fmaf(w3, a3.y, acc1);
    }
    for (; i < n; ++i) {
        int2 e = se[i];
        float2 a = __half22float2(h2[(size_t)e.x * (D / 2) + t]);
        float wv = __int_as_float(e.y);
        acc0 = fmaf(wv, a.x, acc0); acc1 = fmaf(wv, a.y, acc1);
    }
    float2 bv = *(const float2*)&bias[2 * t];
    float f0 = fmaxf(acc0 + bv.x, 0.f), f1 = fmaxf(acc1 + bv.y, 0.f);
    ((__half2*)out)[(size_t)node * (D / 2) + t] = __float22half2_rn(make_float2(f0, f1));
}

// ------ SpMM conv2 + fused cluster MLP + softmax (H2 never materialized) --------
__global__ __launch_bounds__(128) void spmm_cluster_k(const __half* __restrict__ h,
                                                      const int2* __restrict__ edges,
                                                      const int* __restrict__ deg,
                                                      const float* __restrict__ bias,
                                                      const float* __restrict__ Wm,
                                                      const float* __restrict__ bmv,
                                                      float* __restrict__ s_out) {
    int node = blockIdx.x;
    int t = threadIdx.x;                 // 0..127; features 2t, 2t+1
    int n = min(deg[node], PAD);
    __shared__ int2 se[PAD];
    if (t < n) se[t] = edges[(size_t)node * PAD + t];
    __syncthreads();
    const __half2* h2 = (const __half2*)h;
    float acc0 = 0.f, acc1 = 0.f;
    int i = 0;
    for (; i + 4 <= n; i += 4) {
        int2 e0 = se[i], e1 = se[i + 1], e2 = se[i + 2], e3 = se[i + 3];
        float2 a0 = __half22float2(h2[(size_t)e0.x * (D / 2) + t]);
        float2 a1 = __half22float2(h2[(size_t)e1.x * (D / 2) + t]);
        float2 a2 = __half22float2(h2[(size_t)e2.x * (D / 2) + t]);
        float2 a3 = __half22float2(h2[(size_t)e3.x * (D / 2) + t]);
        float w0 = __int_as_float(e0.y), w1 = __int_as_float(e1.y);
        float w2 = __int_as_float(e2.y), w3 = __int_as_float(e3.y);
        acc0 = fmaf(w0, a0.x, acc0); acc1 = fmaf(w0, a0.y, acc1);
        acc0 = fmaf(w1, a1.x, acc0); acc1 = fmaf(w1, a1.y, acc1);
        acc0 = fmaf(w2, a2.x, acc0); acc1 = fmaf(w2, a2.y, acc1);
        acc0 = fmaf(w3, a3.x, acc0); acc1 = fmaf(w3, a3.y, acc1);
    }
    for (; i < n; ++i) {
        int2 e = se[i];
        float2 a = __half22float2(h2[(size_t)e.x * (D / 2) + t]);
        float wv = __int_as_float(e.y);
        acc0 = fmaf(wv, a.x, acc0); acc1 = fmaf(wv, a.y, acc1);
    }
    float2 bv = *(const float2*)&bias[2 * t];
    float f0 = fmaxf(acc0 + bv.x, 0.f), f1 = fmaxf(acc1 + bv.y, 0.f);

    // partial logits: this thread's two features x Wm rows 2t, 2t+1
    float pl[KCL];
    const float4* w0 = (const float4*)&Wm[(size_t)(2 * t) * KCL];
    const float4* w1 = (const float4*)&Wm[(size_t)(2 * t + 1) * KCL];
#pragma unroll
    for (int q = 0; q < 4; ++q) {
        float4 a = w0[q], b = w1[q];
        pl[q * 4 + 0] = f0 * a.x + f1 * b.x;
        pl[q * 4 + 1] = f0 * a.y + f1 * b.y;
        pl[q * 4 + 2] = f0 * a.z + f1 * b.z;
        pl[q * 4 + 3] = f0 * a.w + f1 * b.w;
    }
    // wave butterfly reduce (64 lanes)
#pragma unroll
    for (int off = 32; off; off >>= 1)
#pragma unroll
        for (int j = 0; j < KCL; ++j) pl[j] += __shfl_xor(pl[j], off, 64);
    // cross-wave combine (2 waves)
    __shared__ float xw[2][KCL];
    int wv = t >> 6, ln = t & 63;
    if (ln == 0) {
#pragma unroll
        for (int j = 0; j < KCL; ++j) xw[wv][j] = pl[j];
    }
    __syncthreads();
    if (t == 0) {
        float p[KCL];
        float mx = -1e30f;
#pragma unroll
        for (int j = 0; j < KCL; ++j) {
            p[j] = xw[0][j] + xw[1][j] + bmv[j];
            mx = fmaxf(mx, p[j]);
        }
        float sum = 0.f;
#pragma unroll
        for (int j = 0; j < KCL; ++j) { p[j] = __expf(p[j] - mx); sum += p[j]; }
        float inv = 1.f / sum;
        float* so = &s_out[(size_t)node * KCL];
#pragma unroll
        for (int q = 0; q < 4; ++q)
            *(float4*)&so[q * 4] = make_float4(p[q*4+0] * inv, p[q*4+1] * inv,
                                               p[q*4+2] * inv, p[q*4+3] * inv);
    }
}

// ------- sqloss: 64-block square-sum of s + done-counter loss finale ------------
__global__ __launch_bounds__(256) void sqloss_k(const float* __restrict__ s,
                                                float* __restrict__ diag,
                                                int* __restrict__ done,
                                                float* __restrict__ loss_out, int N) {
    int tid = threadIdx.x;
    int j = tid & 15;                        // cluster (fixed per thread; coalesced)
    int g = tid >> 4;
    int total = N * KCL;
    float acc = 0.f;
    for (int idx = blockIdx.x * 256 + tid; idx < total; idx += gridDim.x * 256) {
        float v = s[idx];
        acc = fmaf(v, v, acc);
    }
    __shared__ float red[16][17];
    red[g][j] = acc;
    __syncthreads();
    if (g == 0) {
        float a = red[0][j];
#pragma unroll
        for (int gg = 1; gg < 16; ++gg) a += red[gg][j];
        atomicAdd(&diag[j], a);
    }
    __threadfence();
    __shared__ int lastFlag;
    if (tid == 0) {
        int old = atomicAdd(done, 1);
        lastFlag = (old == (int)gridDim.x - 1);
    }
    __syncthreads();
    if (lastFlag && tid == 0) {
        __threadfence();
        float sum = 0.f;
#pragma unroll
        for (int jj = 0; jj < KCL; ++jj) {
            float v = atomicAdd(&diag[jj], 0.f);   // coherent read, 16 only
            sum += sqrtf(v + EPS);
        }
        loss_out[0] = -sum / sqrtf((float)N * (float)KCL);
    }
}

extern "C" void kernel_launch(void* const* d_in, const int* in_sizes, int n_in,
                              void* d_out, int out_size, void* d_ws, size_t ws_size,
                              hipStream_t stream) {
    const float* x  = (const float*)d_in[0];
    const float* ew = (const float*)d_in[1];
    const float* W1 = (const float*)d_in[2];
    const float* b1 = (const float*)d_in[3];
    const float* W2 = (const float*)d_in[4];
    const float* b2 = (const float*)d_in[5];
    const float* Wm = (const float*)d_in[6];
    const float* bm = (const float*)d_in[7];
    const int*   ei = (const int*)d_in[8];

    const int N = in_sizes[0] / D;       // 12288
    const int E = in_sizes[1];           // 393216
    const int* src = ei;
    const int* dst = ei + E;

    float* out = (float*)d_out;

    // ws layout (deg | diag | done contiguous -> one memset)
    char* ws = (char*)d_ws;
    __half* G    = (__half*)ws;       ws += (size_t)N * D * 2;      // gemm out (fp16)
    __half* H1   = (__half*)ws;       ws += (size_t)N * D * 2;      // conv1 out (fp16)
    int*   deg   = (int*)ws;          ws += (size_t)N * 4;
    float* diag  = (float*)ws;        ws += 64;
    int*   done  = (int*)ws;          ws += 16;
    int2*  edges = (int2*)ws;         ws += (size_t)N * PAD * 8;
    __half* Wt1  = (__half*)ws;       ws += (size_t)D * D * 2;
    __half* Wt2  = (__half*)ws;       ws += (size_t)D * D * 2;

    // zero deg + diag + done in one memset
    hipMemsetAsync(deg, 0, (size_t)N * 4 + 80, stream);
    // fused weight prep + ELL scatter
    int gE = (E + 255) / 256;
    setup_k<<<512 + gE, 256, 0, stream>>>(W1, W2, Wt1, Wt2,
                                          src, dst, ew, deg, edges, E);

    dim3 ggrid(N / 64, 4);
    // conv1: G = fp16(x @ W1) ; H1 = fp16(relu(scatter(G) + b1))
    gemm_k<float><<<ggrid, 256, 0, stream>>>(x, Wt1, G);
    spmm_k<<<N, 128, 0, stream>>>(G, edges, deg, b1, H1);
    // conv2 gemm: G = fp16(H1 @ W2)
    gemm_k<__half><<<ggrid, 256, 0, stream>>>(H1, Wt2, G);
    // conv2 scatter + cluster MLP + softmax -> s (d_out); H2 never stored
    spmm_cluster_k<<<N, 128, 0, stream>>>(G, edges, deg, b2, Wm, bm, out);
    // loss: 64-block reduce + done-counter finale
    sqloss_k<<<64, 256, 0, stream>>>(out, diag, done, out + (size_t)N * KCL, N);
}

// Round 15
// 213.966 us; speedup vs baseline: 1.1709x; 1.0020x over previous
//
#include <hip/hip_runtime.h>
#include <hip/hip_bf16.h>
#include <hip/hip_fp16.h>

// Problem constants: N=12288, E=393216, D=256, K=16
#define D 256
#define KCL 16
#define EPS 1e-15f
#define PAD 128            // ELL capacity; max degree (Poisson lambda=32) << 128

typedef __attribute__((ext_vector_type(8))) short short8;
typedef __attribute__((ext_vector_type(8))) _Float16 half8;
typedef __attribute__((ext_vector_type(4))) float f32x4;

// ---------------- setup: weight prep fp16 [c][k] (blocks 0..511) + ELL scatter --
__global__ __launch_bounds__(256) void setup_k(const float* __restrict__ W1,
                                               const float* __restrict__ W2,
                                               __half* __restrict__ Wt1,
                                               __half* __restrict__ Wt2,
                                               const int* __restrict__ src,
                                               const int* __restrict__ dst,
                                               const float* __restrict__ ew,
                                               int* __restrict__ deg,
                                               int2* __restrict__ edges, int E) {
    int b = blockIdx.x;
    if (b < 512) {
        const float* W = (b < 256) ? W1 : W2;
        __half* T = (b < 256) ? Wt1 : Wt2;
        int c = b & 255;
        int k = threadIdx.x;
        T[(size_t)c * D + k] = __float2half(W[(size_t)k * D + c]);
    } else {
        int e = (b - 512) * 256 + threadIdx.x;
        if (e < E) {
            int d = dst[e];
            int slot = atomicAdd(&deg[d], 1);
            if (slot < PAD)
                edges[(size_t)d * PAD + slot] = make_int2(src[e], __float_as_int(ew[e]));
        }
    }
}

// ---------------- fp16 MFMA GEMM: C[M,256] = fp16(A) @ fp16(B), fp16 out --------
__device__ __forceinline__ short8 ld8h(const float* p) {
    float4 v0 = *(const float4*)p;
    float4 v1 = *(const float4*)(p + 4);
    float vv[8] = {v0.x, v0.y, v0.z, v0.w, v1.x, v1.y, v1.z, v1.w};
    short8 o;
#pragma unroll
    for (int j = 0; j < 8; ++j) {
        _Float16 h = (_Float16)vv[j];
        o[j] = __builtin_bit_cast(short, h);
    }
    return o;
}
__device__ __forceinline__ short8 ld8h(const __half* p) {
    return *(const short8*)p;
}

template<typename T>
__global__ __launch_bounds__(256) void gemm_k(const T* __restrict__ A,
                                              const __half* __restrict__ Bt,
                                              __half* __restrict__ C) {
    __shared__ short Ah[64][40];          // fp16 bits, 80B row stride
    int tid = threadIdx.x;
    int lane = tid & 63, w = tid >> 6;
    int bm = blockIdx.x * 64, bn = blockIdx.y * 64;
    f32x4 acc[4];
#pragma unroll
    for (int i = 0; i < 4; ++i) acc[i] = (f32x4){0.f, 0.f, 0.f, 0.f};

    int r  = tid >> 2;             // A-stage row 0..63
    int cc = (tid & 3) * 8;        // A-stage k-chunk
    int ar = w * 16 + (lane & 15); // A-frag row
    int kq = (lane >> 4) * 8;      // frag k-chunk

    for (int kk = 0; kk < D; kk += 32) {
        short8 a8 = ld8h(&A[(size_t)(bm + r) * D + kk + cc]);
        __syncthreads();                       // WAR: prev-iter reads done
        *(short8*)&Ah[r][cc] = a8;
        __syncthreads();

        half8 av = __builtin_bit_cast(half8, *(const short8*)&Ah[ar][kq]);
#pragma unroll
        for (int nf = 0; nf < 4; ++nf) {
            int col = bn + nf * 16 + (lane & 15);
            half8 bv = __builtin_bit_cast(half8,
                        *(const short8*)&Bt[(size_t)col * D + kk + kq]);
            acc[nf] = __builtin_amdgcn_mfma_f32_16x16x32_f16(av, bv, acc[nf], 0, 0, 0);
        }
    }
    // epilogue: C/D layout col=lane&15, row=(lane>>4)*4+rr  [m89-verified]
    int rbase = bm + w * 16 + (lane >> 4) * 4;
    int cb = bn + (lane & 15);
#pragma unroll
    for (int nf = 0; nf < 4; ++nf)
#pragma unroll
        for (int rr = 0; rr < 4; ++rr)
            C[(size_t)(rbase + rr) * D + cb + nf * 16] = __float2half(acc[nf][rr]);
}

// -------- SpMM (ELL), wave-per-node: lane owns 4 features, 8B gather/nbr --------
// 256 thr = 4 waves = 4 nodes/block. No __syncthreads: each wave reads only the
// LDS region it wrote (intra-wave lgkmcnt ordering suffices).
__device__ __forceinline__ void spmm_wave(const __half* __restrict__ h,
                                          const int2* __restrict__ edges,
                                          int node, int n, int lane,
                                          int2* se, float f[4]) {
    if (lane < n) se[lane] = edges[(size_t)node * PAD + lane];
    if (lane + 64 < n) se[lane + 64] = edges[(size_t)node * PAD + lane + 64];
    float a0 = 0.f, a1 = 0.f, a2 = 0.f, a3 = 0.f;
    int i = 0;
    for (; i + 4 <= n; i += 4) {
        int2 e0 = se[i], e1 = se[i + 1], e2 = se[i + 2], e3 = se[i + 3];
        float2 r0 = ((const float2*)(h + (size_t)e0.x * D))[lane];
        float2 r1 = ((const float2*)(h + (size_t)e1.x * D))[lane];
        float2 r2 = ((const float2*)(h + (size_t)e2.x * D))[lane];
        float2 r3 = ((const float2*)(h + (size_t)e3.x * D))[lane];
        float w0 = __int_as_float(e0.y), w1 = __int_as_float(e1.y);
        float w2 = __int_as_float(e2.y), w3 = __int_as_float(e3.y);
        float2 p, q;
        p = __half22float2(__builtin_bit_cast(__half2, r0.x));
        q = __half22float2(__builtin_bit_cast(__half2, r0.y));
        a0 = fmaf(w0, p.x, a0); a1 = fmaf(w0, p.y, a1);
        a2 = fmaf(w0, q.x, a2); a3 = fmaf(w0, q.y, a3);
        p = __half22float2(__builtin_bit_cast(__half2, r1.x));
        q = __half22float2(__builtin_bit_cast(__half2, r1.y));
        a0 = fmaf(w1, p.x, a0); a1 = fmaf(w1, p.y, a1);
        a2 = fmaf(w1, q.x, a2); a3 = fmaf(w1, q.y, a3);
        p = __half22float2(__builtin_bit_cast(__half2, r2.x));
        q = __half22float2(__builtin_bit_cast(__half2, r2.y));
        a0 = fmaf(w2, p.x, a0); a1 = fmaf(w2, p.y, a1);
        a2 = fmaf(w2, q.x, a2); a3 = fmaf(w2, q.y, a3);
        p = __half22float2(__builtin_bit_cast(__half2, r3.x));
        q = __half22float2(__builtin_bit_cast(__half2, r3.y));
        a0 = fmaf(w3, p.x, a0); a1 = fmaf(w3, p.y, a1);
        a2 = fmaf(w3, q.x, a2); a3 = fmaf(w3, q.y, a3);
    }
    for (; i < n; ++i) {
        int2 e = se[i];
        float2 r = ((const float2*)(h + (size_t)e.x * D))[lane];
        float wv = __int_as_float(e.y);
        float2 p = __half22float2(__builtin_bit_cast(__half2, r.x));
        float2 q = __half22float2(__builtin_bit_cast(__half2, r.y));
        a0 = fmaf(wv, p.x, a0); a1 = fmaf(wv, p.y, a1);
        a2 = fmaf(wv, q.x, a2); a3 = fmaf(wv, q.y, a3);
    }
    f[0] = a0; f[1] = a1; f[2] = a2; f[3] = a3;
}

__global__ __launch_bounds__(256) void spmm_k(const __half* __restrict__ h,
                                              const int2* __restrict__ edges,
                                              const int* __restrict__ deg,
                                              const float* __restrict__ bias,
                                              __half* __restrict__ out) {
    __shared__ int2 se[4][PAD];
    int tid = threadIdx.x;
    int wv = tid >> 6, lane = tid & 63;
    int node = blockIdx.x * 4 + wv;
    int n = min(deg[node], PAD);
    float f[4];
    spmm_wave(h, edges, node, n, lane, se[wv], f);
    float4 bv = ((const float4*)bias)[lane];
    __half2 o01 = __float22half2_rn(make_float2(fmaxf(f[0] + bv.x, 0.f),
                                                fmaxf(f[1] + bv.y, 0.f)));
    __half2 o23 = __float22half2_rn(make_float2(fmaxf(f[2] + bv.z, 0.f),
                                                fmaxf(f[3] + bv.w, 0.f)));
    ((float2*)(out + (size_t)node * D))[lane] =
        make_float2(__builtin_bit_cast(float, o01), __builtin_bit_cast(float, o23));
}

// ------ SpMM conv2 + fused cluster MLP + softmax (wave-owned node) --------------
__global__ __launch_bounds__(256) void spmm_cluster_k(const __half* __restrict__ h,
                                                      const int2* __restrict__ edges,
                                                      const int* __restrict__ deg,
                                                      const float* __restrict__ bias,
                                                      const float* __restrict__ Wm,
                                                      const float* __restrict__ bmv,
                                                      float* __restrict__ s_out) {
    __shared__ int2 se[4][PAD];
    int tid = threadIdx.x;
    int wv = tid >> 6, lane = tid & 63;
    int node = blockIdx.x * 4 + wv;
    int n = min(deg[node], PAD);
    float f[4];
    spmm_wave(h, edges, node, n, lane, se[wv], f);
    float4 bv = ((const float4*)bias)[lane];
    f[0] = fmaxf(f[0] + bv.x, 0.f); f[1] = fmaxf(f[1] + bv.y, 0.f);
    f[2] = fmaxf(f[2] + bv.z, 0.f); f[3] = fmaxf(f[3] + bv.w, 0.f);

    // partial logits: lane's 4 features x Wm rows 4*lane..4*lane+3
    float pl[KCL];
#pragma unroll
    for (int j = 0; j < KCL; ++j) pl[j] = 0.f;
#pragma unroll
    for (int u = 0; u < 4; ++u) {
        const float4* wr = (const float4*)&Wm[(size_t)(4 * lane + u) * KCL];
        float fv = f[u];
#pragma unroll
        for (int q = 0; q < 4; ++q) {
            float4 a = wr[q];
            pl[q * 4 + 0] = fmaf(fv, a.x, pl[q * 4 + 0]);
            pl[q * 4 + 1] = fmaf(fv, a.y, pl[q * 4 + 1]);
            pl[q * 4 + 2] = fmaf(fv, a.z, pl[q * 4 + 2]);
            pl[q * 4 + 3] = fmaf(fv, a.w, pl[q * 4 + 3]);
        }
    }
    // 64-lane butterfly
#pragma unroll
    for (int off = 32; off; off >>= 1)
#pragma unroll
        for (int j = 0; j < KCL; ++j) pl[j] += __shfl_xor(pl[j], off, 64);
    if (lane == 0) {
        float mx = -1e30f;
#pragma unroll
        for (int j = 0; j < KCL; ++j) { pl[j] += bmv[j]; mx = fmaxf(mx, pl[j]); }
        float sum = 0.f;
#pragma unroll
        for (int j = 0; j < KCL; ++j) { pl[j] = __expf(pl[j] - mx); sum += pl[j]; }
        float inv = 1.f / sum;
        float* so = &s_out[(size_t)node * KCL];
#pragma unroll
        for (int q = 0; q < 4; ++q)
            *(float4*)&so[q * 4] = make_float4(pl[q*4+0] * inv, pl[q*4+1] * inv,
                                               pl[q*4+2] * inv, pl[q*4+3] * inv);
    }
}

// ------- sqloss: 64-block square-sum of s + done-counter loss finale ------------
__global__ __launch_bounds__(256) void sqloss_k(const float* __restrict__ s,
                                                float* __restrict__ diag,
                                                int* __restrict__ done,
                                                float* __restrict__ loss_out, int N) {
    int tid = threadIdx.x;
    int j = tid & 15;
    int g = tid >> 4;
    int total = N * KCL;
    float acc = 0.f;
    for (int idx = blockIdx.x * 256 + tid; idx < total; idx += gridDim.x * 256) {
        float v = s[idx];
        acc = fmaf(v, v, acc);
    }
    __shared__ float red[16][17];
    red[g][j] = acc;
    __syncthreads();
    if (g == 0) {
        float a = red[0][j];
#pragma unroll
        for (int gg = 1; gg < 16; ++gg) a += red[gg][j];
        atomicAdd(&diag[j], a);
    }
    __threadfence();
    __shared__ int lastFlag;
    if (tid == 0) {
        int old = atomicAdd(done, 1);
        lastFlag = (old == (int)gridDim.x - 1);
    }
    __syncthreads();
    if (lastFlag && tid == 0) {
        __threadfence();
        float sum = 0.f;
#pragma unroll
        for (int jj = 0; jj < KCL; ++jj) {
            float v = atomicAdd(&diag[jj], 0.f);   // coherent read, 16 only
            sum += sqrtf(v + EPS);
        }
        loss_out[0] = -sum / sqrtf((float)N * (float)KCL);
    }
}

extern "C" void kernel_launch(void* const* d_in, const int* in_sizes, int n_in,
                              void* d_out, int out_size, void* d_ws, size_t ws_size,
                              hipStream_t stream) {
    const float* x  = (const float*)d_in[0];
    const float* ew = (const float*)d_in[1];
    const float* W1 = (const float*)d_in[2];
    const float* b1 = (const float*)d_in[3];
    const float* W2 = (const float*)d_in[4];
    const float* b2 = (const float*)d_in[5];
    const float* Wm = (const float*)d_in[6];
    const float* bm = (const float*)d_in[7];
    const int*   ei = (const int*)d_in[8];

    const int N = in_sizes[0] / D;       // 12288
    const int E = in_sizes[1];           // 393216
    const int* src = ei;
    const int* dst = ei + E;

    float* out = (float*)d_out;

    // ws layout (deg | diag | done contiguous -> one memset)
    char* ws = (char*)d_ws;
    __half* G    = (__half*)ws;       ws += (size_t)N * D * 2;      // gemm out (fp16)
    __half* H1   = (__half*)ws;       ws += (size_t)N * D * 2;      // conv1 out (fp16)
    int*   deg   = (int*)ws;          ws += (size_t)N * 4;
    float* diag  = (float*)ws;        ws += 64;
    int*   done  = (int*)ws;          ws += 16;
    int2*  edges = (int2*)ws;         ws += (size_t)N * PAD * 8;
    __half* Wt1  = (__half*)ws;       ws += (size_t)D * D * 2;
    __half* Wt2  = (__half*)ws;       ws += (size_t)D * D * 2;

    // zero deg + diag + done in one memset
    hipMemsetAsync(deg, 0, (size_t)N * 4 + 80, stream);
    // fused weight prep + ELL scatter
    int gE = (E + 255) / 256;
    setup_k<<<512 + gE, 256, 0, stream>>>(W1, W2, Wt1, Wt2,
                                          src, dst, ew, deg, edges, E);

    dim3 ggrid(N / 64, 4);
    // conv1: G = fp16(x @ W1) ; H1 = fp16(relu(scatter(G) + b1))
    gemm_k<float><<<ggrid, 256, 0, stream>>>(x, Wt1, G);
    spmm_k<<<N / 4, 256, 0, stream>>>(G, edges, deg, b1, H1);
    // conv2 gemm: G = fp16(H1 @ W2)
    gemm_k<__half><<<ggrid, 256, 0, stream>>>(H1, Wt2, G);
    // conv2 scatter + cluster MLP + softmax -> s (d_out); H2 never stored
    spmm_cluster_k<<<N / 4, 256, 0, stream>>>(G, edges, deg, b2, Wm, bm, out);
    // loss: 64-block reduce + done-counter finale
    sqloss_k<<<64, 256, 0, stream>>>(out, diag, done, out + (size_t)N * KCL, N);
}

// Round 16
// 212.694 us; speedup vs baseline: 1.1779x; 1.0060x over previous
//
#include <hip/hip_runtime.h>
#include <hip/hip_bf16.h>
#include <hip/hip_fp16.h>

// Problem constants: N=12288, E=393216, D=256, K=16
#define D 256
#define KCL 16
#define EPS 1e-15f
#define PAD 128            // ELL capacity; max degree (Poisson lambda=32) << 128
#define HPF 128            // features per half (3.15 MB fp16 half-table, fits 4MB L2)

typedef __attribute__((ext_vector_type(8))) short short8;
typedef __attribute__((ext_vector_type(8))) _Float16 half8;
typedef __attribute__((ext_vector_type(4))) float f32x4;

__device__ __forceinline__ int2 ntload_i2(const int2* p) {
    long long v = __builtin_nontemporal_load((const long long*)p);
    return *(int2*)&v;
}

// ---------------- setup: weight prep fp16 [c][k] (blocks 0..511) + ELL scatter --
__global__ __launch_bounds__(256) void setup_k(const float* __restrict__ W1,
                                               const float* __restrict__ W2,
                                               __half* __restrict__ Wt1,
                                               __half* __restrict__ Wt2,
                                               const int* __restrict__ src,
                                               const int* __restrict__ dst,
                                               const float* __restrict__ ew,
                                               int* __restrict__ deg,
                                               int2* __restrict__ edges, int E) {
    int b = blockIdx.x;
    if (b < 512) {
        const float* W = (b < 256) ? W1 : W2;
        __half* T = (b < 256) ? Wt1 : Wt2;
        int c = b & 255;
        int k = threadIdx.x;
        T[(size_t)c * D + k] = __float2half(W[(size_t)k * D + c]);
    } else {
        int e = (b - 512) * 256 + threadIdx.x;
        if (e < E) {
            int d = dst[e];
            int slot = atomicAdd(&deg[d], 1);
            if (slot < PAD)
                edges[(size_t)d * PAD + slot] = make_int2(src[e], __float_as_int(ew[e]));
        }
    }
}

// ---------------- fp16 MFMA GEMM: C[M,256] = fp16(A) @ fp16(B), fp16 out --------
__device__ __forceinline__ short8 ld8h(const float* p) {
    float4 v0 = *(const float4*)p;
    float4 v1 = *(const float4*)(p + 4);
    float vv[8] = {v0.x, v0.y, v0.z, v0.w, v1.x, v1.y, v1.z, v1.w};
    short8 o;
#pragma unroll
    for (int j = 0; j < 8; ++j) {
        _Float16 h = (_Float16)vv[j];
        o[j] = __builtin_bit_cast(short, h);
    }
    return o;
}
__device__ __forceinline__ short8 ld8h(const __half* p) {
    return *(const short8*)p;
}

template<typename T>
__global__ __launch_bounds__(256) void gemm_k(const T* __restrict__ A,
                                              const __half* __restrict__ Bt,
                                              __half* __restrict__ C) {
    __shared__ short Ah[64][40];          // fp16 bits, 80B row stride
    int tid = threadIdx.x;
    int lane = tid & 63, w = tid >> 6;
    int bm = blockIdx.x * 64, bn = blockIdx.y * 64;
    f32x4 acc[4];
#pragma unroll
    for (int i = 0; i < 4; ++i) acc[i] = (f32x4){0.f, 0.f, 0.f, 0.f};

    int r  = tid >> 2;             // A-stage row 0..63
    int cc = (tid & 3) * 8;        // A-stage k-chunk
    int ar = w * 16 + (lane & 15); // A-frag row
    int kq = (lane >> 4) * 8;      // frag k-chunk

    for (int kk = 0; kk < D; kk += 32) {
        short8 a8 = ld8h(&A[(size_t)(bm + r) * D + kk + cc]);
        __syncthreads();                       // WAR: prev-iter reads done
        *(short8*)&Ah[r][cc] = a8;
        __syncthreads();

        half8 av = __builtin_bit_cast(half8, *(const short8*)&Ah[ar][kq]);
#pragma unroll
        for (int nf = 0; nf < 4; ++nf) {
            int col = bn + nf * 16 + (lane & 15);
            half8 bv = __builtin_bit_cast(half8,
                        *(const short8*)&Bt[(size_t)col * D + kk + kq]);
            acc[nf] = __builtin_amdgcn_mfma_f32_16x16x32_f16(av, bv, acc[nf], 0, 0, 0);
        }
    }
    // epilogue: C/D layout col=lane&15, row=(lane>>4)*4+rr  [m89-verified]
    int rbase = bm + w * 16 + (lane >> 4) * 4;
    int cb = bn + (lane & 15);
#pragma unroll
    for (int nf = 0; nf < 4; ++nf)
#pragma unroll
        for (int rr = 0; rr < 4; ++rr)
            C[(size_t)(rbase + rr) * D + cb + nf * 16] = __float2half(acc[nf][rr]);
}

// -------- SpMM half-feature gather core: lane owns 2 feats (one dword/nbr) ------
// Per-wave LDS staging, nt-loads for edges (don't evict the gather table).
__device__ __forceinline__ void spmm_wave_half(const __half* __restrict__ h,
                                               const int2* __restrict__ edges,
                                               int node, int half, int n, int lane,
                                               int2* se, float& o0, float& o1) {
    if (lane < n) se[lane] = ntload_i2(&edges[(size_t)node * PAD + lane]);
    if (lane + 64 < n) se[lane + 64] = ntload_i2(&edges[(size_t)node * PAD + lane + 64]);
    float a0 = 0.f, a1 = 0.f;
    int i = 0;
    for (; i + 4 <= n; i += 4) {
        int2 e0 = se[i], e1 = se[i + 1], e2 = se[i + 2], e3 = se[i + 3];
        float r0 = ((const float*)(h + (size_t)e0.x * D + half * HPF))[lane];
        float r1 = ((const float*)(h + (size_t)e1.x * D + half * HPF))[lane];
        float r2 = ((const float*)(h + (size_t)e2.x * D + half * HPF))[lane];
        float r3 = ((const float*)(h + (size_t)e3.x * D + half * HPF))[lane];
        float w0 = __int_as_float(e0.y), w1 = __int_as_float(e1.y);
        float w2 = __int_as_float(e2.y), w3 = __int_as_float(e3.y);
        float2 p;
        p = __half22float2(__builtin_bit_cast(__half2, r0));
        a0 = fmaf(w0, p.x, a0); a1 = fmaf(w0, p.y, a1);
        p = __half22float2(__builtin_bit_cast(__half2, r1));
        a0 = fmaf(w1, p.x, a0); a1 = fmaf(w1, p.y, a1);
        p = __half22float2(__builtin_bit_cast(__half2, r2));
        a0 = fmaf(w2, p.x, a0); a1 = fmaf(w2, p.y, a1);
        p = __half22float2(__builtin_bit_cast(__half2, r3));
        a0 = fmaf(w3, p.x, a0); a1 = fmaf(w3, p.y, a1);
    }
    for (; i < n; ++i) {
        int2 e = se[i];
        float r = ((const float*)(h + (size_t)e.x * D + half * HPF))[lane];
        float wv = __int_as_float(e.y);
        float2 p = __half22float2(__builtin_bit_cast(__half2, r));
        a0 = fmaf(wv, p.x, a0); a1 = fmaf(wv, p.y, a1);
    }
    o0 = a0; o1 = a1;
}

// bid -> (half, quad): half pinned to XCD group via bid%8 round-robin heuristic.
__device__ __forceinline__ void decode_bid(int bid, int& half, int& quad) {
    half = (bid & 7) >> 2;
    quad = ((bid >> 3) << 2) | (bid & 3);
}

// -------- SpMM conv1: half-feature, bias+ReLU, fp16 nt-store --------------------
__global__ __launch_bounds__(256) void spmm1_k(const __half* __restrict__ h,
                                               const int2* __restrict__ edges,
                                               const int* __restrict__ deg,
                                               const float* __restrict__ bias,
                                               __half* __restrict__ out) {
    __shared__ int2 se[4][PAD];
    int half, quad;
    decode_bid(blockIdx.x, half, quad);
    int tid = threadIdx.x;
    int wv = tid >> 6, lane = tid & 63;
    int node = quad * 4 + wv;
    int n = min(deg[node], PAD);
    float f0, f1;
    spmm_wave_half(h, edges, node, half, n, lane, se[wv], f0, f1);
    float2 bv = ((const float2*)(bias + half * HPF))[lane];
    __half2 o = __float22half2_rn(make_float2(fmaxf(f0 + bv.x, 0.f),
                                              fmaxf(f1 + bv.y, 0.f)));
    __builtin_nontemporal_store(__builtin_bit_cast(unsigned, o),
        (unsigned*)&((__half2*)(out + (size_t)node * D + half * HPF))[lane]);
}

// -------- SpMM conv2: half-feature, bias+ReLU, partial cluster logits -----------
__global__ __launch_bounds__(256) void spmm2_k(const __half* __restrict__ h,
                                               const int2* __restrict__ edges,
                                               const int* __restrict__ deg,
                                               const float* __restrict__ bias,
                                               const float* __restrict__ Wm,
                                               float* __restrict__ part) {
    __shared__ int2 se[4][PAD];
    int half, quad;
    decode_bid(blockIdx.x, half, quad);
    int tid = threadIdx.x;
    int wv = tid >> 6, lane = tid & 63;
    int node = quad * 4 + wv;
    int n = min(deg[node], PAD);
    float f0, f1;
    spmm_wave_half(h, edges, node, half, n, lane, se[wv], f0, f1);
    float2 bv = ((const float2*)(bias + half * HPF))[lane];
    f0 = fmaxf(f0 + bv.x, 0.f);
    f1 = fmaxf(f1 + bv.y, 0.f);

    // partial logits: lane's 2 features x Wm rows (half*HPF + 2*lane, +1)
    int fidx = half * HPF + 2 * lane;
    float pl[KCL];
    const float4* w0 = (const float4*)&Wm[(size_t)fidx * KCL];
    const float4* w1 = (const float4*)&Wm[(size_t)(fidx + 1) * KCL];
#pragma unroll
    for (int q = 0; q < 4; ++q) {
        float4 a = w0[q], b = w1[q];
        pl[q * 4 + 0] = f0 * a.x + f1 * b.x;
        pl[q * 4 + 1] = f0 * a.y + f1 * b.y;
        pl[q * 4 + 2] = f0 * a.z + f1 * b.z;
        pl[q * 4 + 3] = f0 * a.w + f1 * b.w;
    }
#pragma unroll
    for (int off = 32; off; off >>= 1)
#pragma unroll
        for (int j = 0; j < KCL; ++j) pl[j] += __shfl_xor(pl[j], off, 64);
    if (lane == 0) {
        float* pp = &part[((size_t)node * 2 + half) * KCL];
#pragma unroll
        for (int q = 0; q < 4; ++q)
            *(float4*)&pp[q * 4] = make_float4(pl[q*4+0], pl[q*4+1],
                                               pl[q*4+2], pl[q*4+3]);
    }
}

// ---- combine halves + softmax -> s; fused sq-sum + done-counter loss -----------
__global__ __launch_bounds__(256) void softmax_loss_k(const float* __restrict__ part,
                                                      const float* __restrict__ bmv,
                                                      float* __restrict__ s_out,
                                                      float* __restrict__ diag,
                                                      int* __restrict__ done,
                                                      float* __restrict__ loss_out,
                                                      int N) {
    int tid = threadIdx.x;
    int node = blockIdx.x * 256 + tid;        // grid = N/256 = 48
    int wv = tid >> 6, lane = tid & 63;
    float p[KCL];
    const float4* q0 = (const float4*)&part[(size_t)node * 2 * KCL];
    const float4* q1 = q0 + 4;
    const float4* bb4 = (const float4*)bmv;
    float mx = -1e30f;
#pragma unroll
    for (int q = 0; q < 4; ++q) {
        float4 a = q0[q], b = q1[q], c = bb4[q];
        p[q*4+0] = a.x + b.x + c.x; p[q*4+1] = a.y + b.y + c.y;
        p[q*4+2] = a.z + b.z + c.z; p[q*4+3] = a.w + b.w + c.w;
#pragma unroll
        for (int u = 0; u < 4; ++u) mx = fmaxf(mx, p[q*4+u]);
    }
    float sum = 0.f;
#pragma unroll
    for (int j = 0; j < KCL; ++j) { p[j] = __expf(p[j] - mx); sum += p[j]; }
    float inv = 1.f / sum;
    float sq[KCL];
    float* so = &s_out[(size_t)node * KCL];
#pragma unroll
    for (int q = 0; q < 4; ++q) {
        float s0 = p[q*4+0]*inv, s1 = p[q*4+1]*inv, s2 = p[q*4+2]*inv, s3 = p[q*4+3]*inv;
        *(float4*)&so[q * 4] = make_float4(s0, s1, s2, s3);
        sq[q*4+0] = s0*s0; sq[q*4+1] = s1*s1; sq[q*4+2] = s2*s2; sq[q*4+3] = s3*s3;
    }
    // wave-reduce each cluster's sq, then cross-wave, then one atomic per cluster
#pragma unroll
    for (int off = 32; off; off >>= 1)
#pragma unroll
        for (int j = 0; j < KCL; ++j) sq[j] += __shfl_xor(sq[j], off, 64);
    __shared__ float red[4][KCL];
    if (lane == 0) {
#pragma unroll
        for (int j = 0; j < KCL; ++j) red[wv][j] = sq[j];
    }
    __syncthreads();
    if (tid < KCL)
        atomicAdd(&diag[tid], red[0][tid] + red[1][tid] + red[2][tid] + red[3][tid]);
    __threadfence();
    __shared__ int lastFlag;
    if (tid == 0) {
        int old = atomicAdd(done, 1);
        lastFlag = (old == (int)gridDim.x - 1);
    }
    __syncthreads();
    if (lastFlag && tid == 0) {
        __threadfence();
        float s = 0.f;
#pragma unroll
        for (int jj = 0; jj < KCL; ++jj) {
            float v = atomicAdd(&diag[jj], 0.f);   // coherent read, 16 only
            s += sqrtf(v + EPS);
        }
        loss_out[0] = -s / sqrtf((float)N * (float)KCL);
    }
}

extern "C" void kernel_launch(void* const* d_in, const int* in_sizes, int n_in,
                              void* d_out, int out_size, void* d_ws, size_t ws_size,
                              hipStream_t stream) {
    const float* x  = (const float*)d_in[0];
    const float* ew = (const float*)d_in[1];
    const float* W1 = (const float*)d_in[2];
    const float* b1 = (const float*)d_in[3];
    const float* W2 = (const float*)d_in[4];
    const float* b2 = (const float*)d_in[5];
    const float* Wm = (const float*)d_in[6];
    const float* bm = (const float*)d_in[7];
    const int*   ei = (const int*)d_in[8];

    const int N = in_sizes[0] / D;       // 12288
    const int E = in_sizes[1];           // 393216
    const int* src = ei;
    const int* dst = ei + E;

    float* out = (float*)d_out;

    // ws layout (deg | diag | done contiguous -> one memset)
    char* ws = (char*)d_ws;
    __half* G    = (__half*)ws;       ws += (size_t)N * D * 2;      // gemm out (fp16)
    __half* H1   = (__half*)ws;       ws += (size_t)N * D * 2;      // conv1 out (fp16)
    int*   deg   = (int*)ws;          ws += (size_t)N * 4;
    float* diag  = (float*)ws;        ws += 64;
    int*   done  = (int*)ws;          ws += 16;
    int2*  edges = (int2*)ws;         ws += (size_t)N * PAD * 8;
    __half* Wt1  = (__half*)ws;       ws += (size_t)D * D * 2;
    __half* Wt2  = (__half*)ws;       ws += (size_t)D * D * 2;
    float* part  = (float*)ws;        ws += (size_t)N * 2 * KCL * 4;

    // zero deg + diag + done in one memset
    hipMemsetAsync(deg, 0, (size_t)N * 4 + 80, stream);
    // fused weight prep + ELL scatter
    int gE = (E + 255) / 256;
    setup_k<<<512 + gE, 256, 0, stream>>>(W1, W2, Wt1, Wt2,
                                          src, dst, ew, deg, edges, E);

    dim3 ggrid(N / 64, 4);
    int sgrid = (N / 4) * 2;   // 6144: 2 XCD-pinned halves x 3072 node-quads
    // conv1: G = fp16(x @ W1) ; H1 = fp16(relu(scatter(G) + b1))
    gemm_k<float><<<ggrid, 256, 0, stream>>>(x, Wt1, G);
    spmm1_k<<<sgrid, 256, 0, stream>>>(G, edges, deg, b1, H1);
    // conv2 gemm: G = fp16(H1 @ W2)
    gemm_k<__half><<<ggrid, 256, 0, stream>>>(H1, Wt2, G);
    // conv2 scatter + partial cluster logits (H2 never stored)
    spmm2_k<<<sgrid, 256, 0, stream>>>(G, edges, deg, b2, Wm, part);
    // combine halves + softmax -> s (d_out) + fused loss
    softmax_loss_k<<<48, 256, 0, stream>>>(part, bm, out, diag, done,
                                           out + (size_t)N * KCL, N);
}